// Round 1
// baseline (1580.518 us; speedup 1.0000x reference)
//
#include <hip/hip_runtime.h>
#include <hip/hip_bf16.h>
#include <cstdint>

// Problem constants
#define Bn   1024
#define Tn   128
#define En   300
#define Hn   100
#define Vn   50000
#define G4n  400   // 4*H
#define GPn  512   // padded gate dim (mult of 512 for clean thread mapping)
#define KPn  320   // E padded to mult of 32 (MFMA K)
#define MPn  50048 // V padded to mult of 64
#define NPn  448   // 4H padded to mult of 16 (28 n-subtiles)

typedef __bf16 bf16x8 __attribute__((ext_vector_type(8)));
typedef float  f32x4  __attribute__((ext_vector_type(4)));

// workspace byte offsets (total 94,149,120 B)
#define OFF_TABLE 0ull          // bf16 [Vn][G4n]           40,000,000
#define OFF_OUTH  40000000ull   // f32  [Bn][Tn][Hn]        52,428,800
#define OFF_EMBB  40000000ull   // bf16 [MPn][KPn] (ALIASED with OUTH; dead before k_lstm)
#define OFF_WIHB  92428800ull   // bf16 [NPn][KPn]             286,720
#define OFF_WT    92715520ull   // f32  [Hn][GPn]  W_hh^T      204,800
#define OFF_LV    92920320ull   // f32  [Bn][Hn]               409,600
#define OFF_PN    93329920ull   // f32  [Bn][Hn]               409,600
#define OFF_NEG   93739520ull   // f32  [Bn][Hn]               409,600

__device__ __forceinline__ float sigf(float x) { return 1.0f / (1.0f + __expf(-x)); }
__device__ __forceinline__ float tanhfast(float x) { return 1.0f - 2.0f / (__expf(2.0f * x) + 1.0f); }

// ---------------- K0a: emb (V,E) f32 -> padded bf16 (MPn,KPn) ----------------
__global__ void k_cvt_emb(const float* __restrict__ emb, __hip_bfloat16* __restrict__ embb) {
    int m = blockIdx.x;
    for (int k = threadIdx.x; k < KPn; k += 256) {
        float v = (m < Vn && k < En) ? emb[(size_t)m * En + k] : 0.0f;
        embb[(size_t)m * KPn + k] = __float2bfloat16(v);
    }
}

// ---------------- K0b: W_ih -> padded bf16; W_hh -> transposed padded f32 ----
__global__ void k_prep(const float* __restrict__ W_ih, const float* __restrict__ W_hh,
                       __hip_bfloat16* __restrict__ wihb, float* __restrict__ wt) {
    int idx = blockIdx.x * 256 + threadIdx.x;
    if (idx < NPn * KPn) {
        int n = idx / KPn, k = idx - n * KPn;
        float v = (n < G4n && k < En) ? W_ih[(size_t)n * En + k] : 0.0f;
        wihb[idx] = __float2bfloat16(v);
    }
    if (idx < Hn * GPn) {
        int k = idx / GPn, j = idx - k * GPn;
        wt[idx] = (j < G4n) ? W_hh[(size_t)j * Hn + k] : 0.0f;  // wt[k][j] = W_hh[j][k]
    }
}

// ---------------- K1: table = emb @ W_ih^T + (b_ih+b_hh), bf16 MFMA ----------
// block: 256 thr = 4 waves; wave w owns 16 M-rows (m0+w*16) x all 448 N (28 subtiles)
__global__ __launch_bounds__(256, 2) void k_table(
    const __hip_bfloat16* __restrict__ embb, const __hip_bfloat16* __restrict__ wihb,
    const float* __restrict__ b_ih, const float* __restrict__ b_hh,
    __hip_bfloat16* __restrict__ table) {
    const int wv = threadIdx.x >> 6, lane = threadIdx.x & 63;
    const int m0 = blockIdx.x * 64 + wv * 16;
    const int row16 = lane & 15, kq = lane >> 4;  // kq in 0..3
    f32x4 acc[28];
#pragma unroll
    for (int i = 0; i < 28; i++) acc[i] = (f32x4){0.f, 0.f, 0.f, 0.f};
    const uint4* A = (const uint4*)embb;
    const uint4* Bm = (const uint4*)wihb;
#pragma unroll
    for (int kk = 0; kk < KPn / 32; kk++) {
        const int ko = kk * 32 + kq * 8;
        uint4 araw = A[((size_t)(m0 + row16) * KPn + ko) >> 3];
        bf16x8 af = __builtin_bit_cast(bf16x8, araw);
#pragma unroll
        for (int ns = 0; ns < 28; ns++) {
            uint4 braw = Bm[((size_t)(ns * 16 + row16) * KPn + ko) >> 3];
            bf16x8 bf = __builtin_bit_cast(bf16x8, braw);
            acc[ns] = __builtin_amdgcn_mfma_f32_16x16x32_bf16(af, bf, acc[ns], 0, 0, 0);
        }
    }
    const int crow = kq * 4;  // C/D: row=(lane>>4)*4+r, col=lane&15
#pragma unroll
    for (int ns = 0; ns < 28; ns++) {
        int n = ns * 16 + row16;
        if (n < G4n) {
            float bias = b_ih[n] + b_hh[n];
#pragma unroll
            for (int r = 0; r < 4; r++) {
                int m = m0 + crow + r;
                if (m < Vn) table[(size_t)m * G4n + n] = __float2bfloat16(acc[ns][r] + bias);
            }
        }
    }
}

// ---------------- K2: label_vec = emb[lid] @ ll_W^T + ll_b (f32) -------------
__global__ void k_label(const int* __restrict__ lwid, const float* __restrict__ emb,
                        const float* __restrict__ llW, const float* __restrict__ llb,
                        float* __restrict__ lv) {
    __shared__ float er[En];
    int b = blockIdx.x;
    int lid = lwid[b];
    for (int k = threadIdx.x; k < En; k += 128) er[k] = emb[(size_t)lid * En + k];
    __syncthreads();
    int h = threadIdx.x;
    if (h < Hn) {
        float acc = llb[h];
        for (int k = 0; k < En; k++) acc += er[k] * llW[(size_t)h * En + k];
        lv[(size_t)b * Hn + h] = acc;
    }
}

// ---------------- K3: fused LSTM + last/scores/topk/pos/per_neg --------------
// block: 256 thr, 4 batch elems. W_hh^T streamed from L2 in 10 double-buffered
// 10-row slabs per step. Gates GEMM: thread = (jq=tid&127 -> 4 j's, ks=tid>>7 k-split).
__global__ __launch_bounds__(256, 1) void k_lstm(
    const int* __restrict__ word_id, const int* __restrict__ sen_len,
    const __hip_bfloat16* __restrict__ table, const float* __restrict__ wt,
    const float* __restrict__ lv, const float* __restrict__ linW,
    const float* __restrict__ linb, float* __restrict__ out_h,
    float* __restrict__ per_neg, float* __restrict__ d_out) {
    __shared__ float wt_sh[2][10][GPn];   // 40 KB
    __shared__ float g_sh[4][GPn];        // 8 KB
    __shared__ float ht_sh[Hn][4];        // h transposed: [u][mb]
    __shared__ float lt_sh[Hn][4];        // label_vec transposed
    __shared__ float scores_sh[4][Tn];
    __shared__ float pos_sh[4][Hn];
    __shared__ float lasth_sh[4][Hn];
    __shared__ float tk_val[4][4];
    __shared__ int   tk_idx[4][4];

    const int tid = threadIdx.x;
    const int b0 = blockIdx.x * 4;
    int slen[4];
#pragma unroll
    for (int mb = 0; mb < 4; mb++) slen[mb] = sen_len[b0 + mb];
    for (int i = tid; i < 4 * Hn; i += 256) { int mb = i / Hn, u = i - mb * Hn; lt_sh[u][mb] = lv[(size_t)(b0 + mb) * Hn + u]; }
    for (int i = tid; i < Hn * 4; i += 256) ((float*)ht_sh)[i] = 0.0f;

    const int jq = tid & 127;  // j quad: j = jq*4
    const int ks = tid >> 7;   // k-split 0/1
    float c_reg[2] = {0.f, 0.f};
    float sumh[2] = {0.f, 0.f};

    for (int t = 0; t < Tn; t++) {
        // ---- gather X (bf16 table rows) into g_sh as f32; pad j>=400 with 0
        int wid[4];
#pragma unroll
        for (int mb = 0; mb < 4; mb++) wid[mb] = word_id[(b0 + mb) * Tn + t];
#pragma unroll
        for (int i = 0; i < 4; i++) {
            int idx = tid + i * 256;
            int mb = idx >> 8, jp = idx & 255;
            int j = jp * 2;
            float v0 = 0.f, v1 = 0.f;
            if (j < G4n) {
                uint32_t pr = *(const uint32_t*)((const uint16_t*)table + (size_t)wid[mb] * G4n + j);
                v0 = __uint_as_float(pr << 16);
                v1 = __uint_as_float(pr & 0xffff0000u);
            }
            g_sh[mb][j] = v0;
            g_sh[mb][j + 1] = v1;
        }
        float acc[4][4];
#pragma unroll
        for (int a = 0; a < 4; a++)
#pragma unroll
            for (int b = 0; b < 4; b++) acc[a][b] = 0.f;
        // ---- prologue: stage slab 0
        {
            const float4* src = (const float4*)wt;
            float4* dst = (float4*)&wt_sh[0][0][0];
            for (int i = tid; i < 1280; i += 256) dst[i] = src[i];
        }
        __syncthreads();
        // ---- 10 slabs of 10 k-rows, double buffered
        for (int s = 0; s < 10; s++) {
            if (s + 1 < 10) {
                const float4* src = (const float4*)(wt + (size_t)(s + 1) * 10 * GPn);
                float4* dst = (float4*)&wt_sh[(s + 1) & 1][0][0];
                for (int i = tid; i < 1280; i += 256) dst[i] = src[i];
            }
            const float(*buf)[GPn] = wt_sh[s & 1];
#pragma unroll
            for (int kk = 0; kk < 5; kk++) {
                int kc = ks * 5 + kk;
                float4 w4 = *(const float4*)&buf[kc][jq * 4];
                float4 h4 = *(const float4*)&ht_sh[s * 10 + kc][0];  // broadcast 16B: h for mb 0..3
                acc[0][0] += h4.x * w4.x; acc[0][1] += h4.x * w4.y; acc[0][2] += h4.x * w4.z; acc[0][3] += h4.x * w4.w;
                acc[1][0] += h4.y * w4.x; acc[1][1] += h4.y * w4.y; acc[1][2] += h4.y * w4.z; acc[1][3] += h4.y * w4.w;
                acc[2][0] += h4.z * w4.x; acc[2][1] += h4.z * w4.y; acc[2][2] += h4.z * w4.z; acc[2][3] += h4.z * w4.w;
                acc[3][0] += h4.w * w4.x; acc[3][1] += h4.w * w4.y; acc[3][2] += h4.w * w4.z; acc[3][3] += h4.w * w4.w;
            }
            __syncthreads();
        }
        // ---- reduce the 2-way k-split into g_sh (two phases, race-free)
        if (ks == 0) {
#pragma unroll
            for (int mb = 0; mb < 4; mb++) {
                float4 g = *(float4*)&g_sh[mb][jq * 4];
                g.x += acc[mb][0]; g.y += acc[mb][1]; g.z += acc[mb][2]; g.w += acc[mb][3];
                *(float4*)&g_sh[mb][jq * 4] = g;
            }
        }
        __syncthreads();
        if (ks == 1) {
#pragma unroll
            for (int mb = 0; mb < 4; mb++) {
                float4 g = *(float4*)&g_sh[mb][jq * 4];
                g.x += acc[mb][0]; g.y += acc[mb][1]; g.z += acc[mb][2]; g.w += acc[mb][3];
                *(float4*)&g_sh[mb][jq * 4] = g;
            }
        }
        __syncthreads();
        // ---- elementwise gates -> c,h ; store h; track sumh/lasth
#pragma unroll
        for (int it = 0; it < 2; it++) {
            int task = tid + it * 256;
            if (task < 400) {
                int mb = task / 100, u = task - mb * 100;
                float gi = g_sh[mb][u], gf = g_sh[mb][u + 100], gg = g_sh[mb][u + 200], go = g_sh[mb][u + 300];
                float c = sigf(gf) * c_reg[it] + sigf(gi) * tanhfast(gg);
                c_reg[it] = c;
                float hh = sigf(go) * tanhfast(c);
                ht_sh[u][mb] = hh;
                out_h[((size_t)(b0 + mb) * Tn + t) * Hn + u] = hh;
                if (t < slen[mb]) sumh[it] += hh;
                if (t == slen[mb] - 1) lasth_sh[mb][u] = hh;
            }
        }
        __syncthreads();
        // ---- scores[mb][t] = dot(h, label_vec)
        if (tid < 128) {
            int mb = tid >> 5, l5 = tid & 31;
            float p = 0.f;
            for (int u = l5; u < Hn; u += 32) p += ht_sh[u][mb] * lt_sh[u][mb];
            for (int off = 16; off; off >>= 1) p += __shfl_down(p, off, 32);
            if (l5 == 0) scores_sh[mb][t] = p;
        }
        // no sync needed: next writers of ht_sh/g_sh are separated by slab syncs
    }
    __syncthreads();
    // ---- top-4 per mb (wave wv handles mb=wv); tie-break: smaller index
    {
        int wv = tid >> 6, lane = tid & 63;
        int mb = wv;
        float s0 = (lane < slen[mb]) ? scores_sh[mb][lane] : -1e30f;
        float s1 = (lane + 64 < slen[mb]) ? scores_sh[mb][lane + 64] : -1e30f;
        bool tk0 = false, tk1 = false;
#pragma unroll
        for (int p = 0; p < 4; p++) {
            float v = tk0 ? -1e30f : s0;
            int ix = lane;
            float v1 = tk1 ? -1e30f : s1;
            if (v1 > v) { v = v1; ix = lane + 64; }
            for (int off = 32; off; off >>= 1) {
                float ov = __shfl_down(v, off, 64);
                int oi = __shfl_down(ix, off, 64);
                if (ov > v || (ov == v && oi < ix)) { v = ov; ix = oi; }
            }
            v = __shfl(v, 0, 64);
            ix = __shfl(ix, 0, 64);
            if (lane == 0) { tk_val[mb][p] = v; tk_idx[mb][p] = ix; }
            if (ix == lane) tk0 = true;
            if (ix == lane + 64) tk1 = true;
        }
    }
    __syncthreads();
    // ---- pos = sum vals*h[idx]; per_neg = sumh_valid - sum h[idx]
#pragma unroll
    for (int it = 0; it < 2; it++) {
        int task = tid + it * 256;
        if (task < 400) {
            int mb = task / 100, u = task - mb * 100;
            float pos = 0.f, nsum = sumh[it];
#pragma unroll
            for (int p = 0; p < 4; p++) {
                int ix = tk_idx[mb][p];
                float r = out_h[((size_t)(b0 + mb) * Tn + ix) * Hn + u];  // same thread wrote these
                pos += tk_val[mb][p] * r;
                nsum -= r;
            }
            pos_sh[mb][u] = pos;
            per_neg[(size_t)(b0 + mb) * Hn + u] = nsum;
        }
    }
    __syncthreads();
    // ---- projections: out_f = lin(lasth), l_rep = lin(pos)
    if (tid < 48) {
        int which = tid / 24;  // 0: out_f, 1: l_rep
        int r = tid - which * 24;
        int mb = r / 6, o = r - mb * 6;
        const float* src = which ? &pos_sh[mb][0] : &lasth_sh[mb][0];
        float acc = linb[o];
        for (int u = 0; u < Hn; u++) acc += src[u] * linW[o * Hn + u];
        d_out[(which ? (Bn * 6) : 0) + (b0 + mb) * 6 + o] = acc;
    }
}

// ---------------- K4: batch cumsum of per_neg (one block per h-dim) ----------
__global__ __launch_bounds__(1024) void k_scan(const float* __restrict__ pn, float* __restrict__ neg) {
    __shared__ float s[Bn];
    int u = blockIdx.x, t = threadIdx.x;
    s[t] = pn[(size_t)t * Hn + u];
    __syncthreads();
    for (int off = 1; off < Bn; off <<= 1) {
        float add = (t >= off) ? s[t - off] : 0.f;
        __syncthreads();
        s[t] += add;
        __syncthreads();
    }
    neg[(size_t)t * Hn + u] = s[t];
}

// ---------------- K5: r_rep = neg @ lin_W^T + lin_b --------------------------
__global__ void k_rrep(const float* __restrict__ neg, const float* __restrict__ linW,
                       const float* __restrict__ linb, float* __restrict__ d_out) {
    int gid = blockIdx.x * 256 + threadIdx.x;
    if (gid < Bn * 6) {
        int b = gid / 6, o = gid - b * 6;
        float acc = linb[o];
        for (int u = 0; u < Hn; u++) acc += neg[(size_t)b * Hn + u] * linW[o * Hn + u];
        d_out[2 * Bn * 6 + gid] = acc;
    }
}

extern "C" void kernel_launch(void* const* d_in, const int* in_sizes, int n_in,
                              void* d_out, int out_size, void* d_ws, size_t ws_size,
                              hipStream_t stream) {
    const int*   word_id = (const int*)d_in[0];
    const int*   sen_len = (const int*)d_in[1];
    const int*   lwid    = (const int*)d_in[2];
    const float* emb     = (const float*)d_in[3];
    const float* W_ih    = (const float*)d_in[4];
    const float* W_hh    = (const float*)d_in[5];
    const float* b_ih    = (const float*)d_in[6];
    const float* b_hh    = (const float*)d_in[7];
    const float* linW    = (const float*)d_in[8];
    const float* linb    = (const float*)d_in[9];
    const float* llW     = (const float*)d_in[10];
    const float* llb     = (const float*)d_in[11];

    char* ws = (char*)d_ws;
    __hip_bfloat16* table = (__hip_bfloat16*)(ws + OFF_TABLE);
    float*          out_h = (float*)(ws + OFF_OUTH);
    __hip_bfloat16* embb  = (__hip_bfloat16*)(ws + OFF_EMBB);  // aliased with out_h (disjoint lifetime)
    __hip_bfloat16* wihb  = (__hip_bfloat16*)(ws + OFF_WIHB);
    float*          wt    = (float*)(ws + OFF_WT);
    float*          lv    = (float*)(ws + OFF_LV);
    float*          pn    = (float*)(ws + OFF_PN);
    float*          neg   = (float*)(ws + OFF_NEG);
    float*          outp  = (float*)d_out;

    k_cvt_emb<<<MPn, 256, 0, stream>>>(emb, embb);
    k_prep<<<(NPn * KPn + 255) / 256, 256, 0, stream>>>(W_ih, W_hh, wihb, wt);
    k_table<<<MPn / 64, 256, 0, stream>>>(embb, wihb, b_ih, b_hh, table);
    k_label<<<Bn, 128, 0, stream>>>(lwid, emb, llW, llb, lv);
    k_lstm<<<Bn / 4, 256, 0, stream>>>(word_id, sen_len, table, wt, lv, linW, linb, out_h, pn, outp);
    k_scan<<<Hn, 1024, 0, stream>>>(pn, neg);
    k_rrep<<<(Bn * 6 + 255) / 256, 256, 0, stream>>>(neg, linW, linb, outp);
}

// Round 2
// 568.766 us; speedup vs baseline: 2.7789x; 2.7789x over previous
//
#include <hip/hip_runtime.h>
#include <hip/hip_bf16.h>
#include <cstdint>

// Problem constants
#define Bn   1024
#define Tn   128
#define En   300
#define Hn   100
#define Vn   50000
#define G4n  400   // 4*H
#define KPn  320   // E padded to mult of 32 (MFMA K)
#define MPn  50048 // V padded to mult of 64
#define NPn  448   // 4H padded to mult of 16 (28 n-subtiles)

typedef __bf16 bf16x8 __attribute__((ext_vector_type(8)));
typedef float  f32x4  __attribute__((ext_vector_type(4)));
typedef _Float16 half2v __attribute__((ext_vector_type(2)));

#if __has_builtin(__builtin_amdgcn_fdot2)
__device__ __forceinline__ float DOT2(half2v w, half2v h, float c) {
    return __builtin_amdgcn_fdot2(w, h, c, false);
}
#else
__device__ __forceinline__ float DOT2(half2v w, half2v h, float c) {
    return c + (float)w.x * (float)h.x + (float)w.y * (float)h.y;
}
#endif

// workspace byte offsets (total 94,024,320 B; round-1 used 94,149,120 OK)
#define OFF_TABLE 0ull          // bf16 [Vn][G4n]           40,000,000
#define OFF_OUTH  40000000ull   // f32  [Bn][Tn][Hn]        52,428,800
#define OFF_EMBB  40000000ull   // bf16 [MPn][KPn] (ALIASED with OUTH; dead before k_lstm)
#define OFF_WIHB  92428800ull   // bf16 [NPn][KPn]             286,720
#define OFF_WF16  92715520ull   // uint [G4n][50] f16-pairs     80,000
#define OFF_LV    92795520ull   // f32  [Bn][Hn]               409,600
#define OFF_PN    93205120ull   // f32  [Bn][Hn]               409,600
#define OFF_NEG   93614720ull   // f32  [Bn][Hn]               409,600

__device__ __forceinline__ float sigf(float x) { return 1.0f / (1.0f + __expf(-x)); }
__device__ __forceinline__ float tanhfast(float x) { return 1.0f - 2.0f / (__expf(2.0f * x) + 1.0f); }

// ---------------- K0a: emb (V,E) f32 -> padded bf16 (MPn,KPn) ----------------
__global__ void k_cvt_emb(const float* __restrict__ emb, __hip_bfloat16* __restrict__ embb) {
    int m = blockIdx.x;
    for (int k = threadIdx.x; k < KPn; k += 256) {
        float v = (m < Vn && k < En) ? emb[(size_t)m * En + k] : 0.0f;
        embb[(size_t)m * KPn + k] = __float2bfloat16(v);
    }
}

// ---------------- K0b: W_ih -> padded bf16; W_hh -> f16 k-pairs --------------
__global__ void k_prep(const float* __restrict__ W_ih, const float* __restrict__ W_hh,
                       __hip_bfloat16* __restrict__ wihb, uint32_t* __restrict__ wf16) {
    int idx = blockIdx.x * 256 + threadIdx.x;
    if (idx < NPn * KPn) {
        int n = idx / KPn, k = idx - n * KPn;
        float v = (n < G4n && k < En) ? W_ih[(size_t)n * En + k] : 0.0f;
        wihb[idx] = __float2bfloat16(v);
    }
    if (idx < G4n * 50) {
        int j = idx / 50, kp = idx - j * 50;
        half2v p;
        p.x = (_Float16)W_hh[(size_t)j * Hn + 2 * kp];
        p.y = (_Float16)W_hh[(size_t)j * Hn + 2 * kp + 1];
        wf16[idx] = __builtin_bit_cast(uint32_t, p);
    }
}

// ---------------- K1: table = emb @ W_ih^T + (b_ih+b_hh), bf16 MFMA ----------
__global__ __launch_bounds__(256, 2) void k_table(
    const __hip_bfloat16* __restrict__ embb, const __hip_bfloat16* __restrict__ wihb,
    const float* __restrict__ b_ih, const float* __restrict__ b_hh,
    __hip_bfloat16* __restrict__ table) {
    const int wv = threadIdx.x >> 6, lane = threadIdx.x & 63;
    const int m0 = blockIdx.x * 64 + wv * 16;
    const int row16 = lane & 15, kq = lane >> 4;
    f32x4 acc[28];
#pragma unroll
    for (int i = 0; i < 28; i++) acc[i] = (f32x4){0.f, 0.f, 0.f, 0.f};
    const uint4* A = (const uint4*)embb;
    const uint4* Bm = (const uint4*)wihb;
#pragma unroll
    for (int kk = 0; kk < KPn / 32; kk++) {
        const int ko = kk * 32 + kq * 8;
        uint4 araw = A[((size_t)(m0 + row16) * KPn + ko) >> 3];
        bf16x8 af = __builtin_bit_cast(bf16x8, araw);
#pragma unroll
        for (int ns = 0; ns < 28; ns++) {
            uint4 braw = Bm[((size_t)(ns * 16 + row16) * KPn + ko) >> 3];
            bf16x8 bf = __builtin_bit_cast(bf16x8, braw);
            acc[ns] = __builtin_amdgcn_mfma_f32_16x16x32_bf16(af, bf, acc[ns], 0, 0, 0);
        }
    }
    const int crow = kq * 4;  // C/D: row=(lane>>4)*4+r, col=lane&15
#pragma unroll
    for (int ns = 0; ns < 28; ns++) {
        int n = ns * 16 + row16;
        if (n < G4n) {
            float bias = b_ih[n] + b_hh[n];
#pragma unroll
            for (int r = 0; r < 4; r++) {
                int m = m0 + crow + r;
                if (m < Vn) table[(size_t)m * G4n + n] = __float2bfloat16(acc[ns][r] + bias);
            }
        }
    }
}

// ---------------- K2: label_vec = emb[lid] @ ll_W^T + ll_b (f32) -------------
__global__ void k_label(const int* __restrict__ lwid, const float* __restrict__ emb,
                        const float* __restrict__ llW, const float* __restrict__ llb,
                        float* __restrict__ lv) {
    __shared__ float er[En];
    int b = blockIdx.x;
    int lid = lwid[b];
    for (int k = threadIdx.x; k < En; k += 128) er[k] = emb[(size_t)lid * En + k];
    __syncthreads();
    int h = threadIdx.x;
    if (h < Hn) {
        float acc = llb[h];
        for (int k = 0; k < En; k++) acc += er[k] * llW[(size_t)h * En + k];
        lv[(size_t)b * Hn + h] = acc;
    }
}

// ---------------- K3: fused LSTM + last/scores/topk/pos/per_neg --------------
// W_hh held in VGPRs (f16 pairs, 100 dwords/thread, thread owns gate rows
// j=2*tid, 2*tid+1). h broadcast from LDS as f16 pairs. 2 barriers/step.
// x-gather (table rows) prefetched one step ahead into registers.
__global__ __launch_bounds__(256, 1) void k_lstm(
    const int* __restrict__ word_id, const int* __restrict__ sen_len,
    const __hip_bfloat16* __restrict__ table, const uint32_t* __restrict__ wf16,
    const float* __restrict__ lv, const float* __restrict__ linW,
    const float* __restrict__ linb, float* __restrict__ out_h,
    float* __restrict__ per_neg, float* __restrict__ d_out) {
    __shared__ float g_sh[4][G4n];        // gates, f32
    __shared__ uint32_t hp[50][4];        // h as f16 pairs: hp[kp][mb] = (h[2kp],h[2kp+1])
    __shared__ float ht_sh[Hn][4];        // h f32 transposed (for scores)
    __shared__ float lt_sh[Hn][4];
    __shared__ float scores_sh[4][Tn];
    __shared__ int   widc[4][Tn];
    __shared__ float pos_sh[4][Hn];
    __shared__ float lasth_sh[4][Hn];
    __shared__ float tk_val[4][4];
    __shared__ int   tk_idx[4][4];

    const int tid = threadIdx.x;
    const int b0 = blockIdx.x * 4;
    int slen[4];
#pragma unroll
    for (int mb = 0; mb < 4; mb++) slen[mb] = sen_len[b0 + mb];
    for (int i = tid; i < 4 * Hn; i += 256) { int mb = i / Hn, u = i - mb * Hn; lt_sh[u][mb] = lv[(size_t)(b0 + mb) * Hn + u]; }
    for (int i = tid; i < 200; i += 256) ((uint32_t*)hp)[i] = 0u;
    for (int i = tid; i < 4 * Tn; i += 256) { int mb = i >> 7, t = i & 127; widc[mb][t] = word_id[(b0 + mb) * Tn + t]; }

    // ---- W_hh slice -> registers: rows j0, j0+1; 100 contiguous dwords
    const int j0 = tid * 2;
    uint32_t wf[100];
    if (tid < 200) {
        const uint4* wp = (const uint4*)(wf16 + (size_t)j0 * 50);
#pragma unroll
        for (int q = 0; q < 25; q++) {
            uint4 r = wp[q];
            wf[q * 4] = r.x; wf[q * 4 + 1] = r.y; wf[q * 4 + 2] = r.z; wf[q * 4 + 3] = r.w;
        }
    } else {
#pragma unroll
        for (int q = 0; q < 100; q++) wf[q] = 0u;
    }
    __syncthreads();

    // ---- prefetch x for t=0
    const uint16_t* tb16 = (const uint16_t*)table;
    uint32_t xr[4];
    if (tid < 200) {
#pragma unroll
        for (int mb = 0; mb < 4; mb++)
            xr[mb] = *(const uint32_t*)(tb16 + (size_t)widc[mb][0] * G4n + j0);
    }

    float c_reg[2] = {0.f, 0.f};
    float sumh[2] = {0.f, 0.f};

    for (int t = 0; t < Tn; t++) {
        // ---- phase A: gates GEMM from register W, broadcast h pairs
        float acc00 = 0.f, acc01 = 0.f, acc10 = 0.f, acc11 = 0.f;
        float acc20 = 0.f, acc21 = 0.f, acc30 = 0.f, acc31 = 0.f;
#pragma unroll
        for (int kp = 0; kp < 50; kp++) {
            uint4 h4 = *(const uint4*)&hp[kp][0];
            half2v wa = __builtin_bit_cast(half2v, wf[kp]);
            half2v wb = __builtin_bit_cast(half2v, wf[50 + kp]);
            half2v h0 = __builtin_bit_cast(half2v, h4.x);
            half2v h1 = __builtin_bit_cast(half2v, h4.y);
            half2v h2 = __builtin_bit_cast(half2v, h4.z);
            half2v h3 = __builtin_bit_cast(half2v, h4.w);
            acc00 = DOT2(wa, h0, acc00); acc01 = DOT2(wb, h0, acc01);
            acc10 = DOT2(wa, h1, acc10); acc11 = DOT2(wb, h1, acc11);
            acc20 = DOT2(wa, h2, acc20); acc21 = DOT2(wb, h2, acc21);
            acc30 = DOT2(wa, h3, acc30); acc31 = DOT2(wb, h3, acc31);
        }
        if (tid < 200) {
            float a0[4] = {acc00, acc10, acc20, acc30};
            float a1[4] = {acc01, acc11, acc21, acc31};
#pragma unroll
            for (int mb = 0; mb < 4; mb++) {
                float xlo = __uint_as_float(xr[mb] << 16);
                float xhi = __uint_as_float(xr[mb] & 0xffff0000u);
                float2 gv; gv.x = a0[mb] + xlo; gv.y = a1[mb] + xhi;
                *(float2*)&g_sh[mb][j0] = gv;
            }
            // issue next step's gather (consumed next iteration, hidden under GEMM+B+C)
            int tn = (t + 1 < Tn) ? t + 1 : Tn - 1;
#pragma unroll
            for (int mb = 0; mb < 4; mb++)
                xr[mb] = *(const uint32_t*)(tb16 + (size_t)widc[mb][tn] * G4n + j0);
        }
        __syncthreads();  // S1: g_sh ready
        // ---- phase B: elementwise gates -> c,h; write ht_sh, hp halves, out_h
#pragma unroll
        for (int it = 0; it < 2; it++) {
            int task = tid + it * 256;
            if (task < 400) {
                int mb = task / 100, u = task - mb * 100;
                float gi = g_sh[mb][u], gf = g_sh[mb][u + 100], gg = g_sh[mb][u + 200], go = g_sh[mb][u + 300];
                float c = sigf(gf) * c_reg[it] + sigf(gi) * tanhfast(gg);
                c_reg[it] = c;
                float hh = sigf(go) * tanhfast(c);
                ht_sh[u][mb] = hh;
                ((_Float16*)hp)[((u >> 1) * 4 + mb) * 2 + (u & 1)] = (_Float16)hh;
                out_h[((size_t)(b0 + mb) * Tn + t) * Hn + u] = hh;
                if (t < slen[mb]) sumh[it] += hh;
                if (t == slen[mb] - 1) lasth_sh[mb][u] = hh;
            }
        }
        __syncthreads();  // S2: h ready (hp for next A, ht_sh for C)
        // ---- phase C: scores[mb][t] = dot(h, label_vec)
        if (tid < 128) {
            int mb = tid >> 5, l5 = tid & 31;
            float p = 0.f;
            for (int u = l5; u < Hn; u += 32) p += ht_sh[u][mb] * lt_sh[u][mb];
            for (int off = 16; off; off >>= 1) p += __shfl_down(p, off, 32);
            if (l5 == 0) scores_sh[mb][t] = p;
        }
        // no barrier: next B's ht_sh writes are fenced by next S1
    }
    __syncthreads();
    // ---- top-4 per mb (wave wv handles mb=wv); tie-break: smaller index
    {
        int wv = tid >> 6, lane = tid & 63;
        int mb = wv;
        float s0 = (lane < slen[mb]) ? scores_sh[mb][lane] : -1e30f;
        float s1 = (lane + 64 < slen[mb]) ? scores_sh[mb][lane + 64] : -1e30f;
        bool tk0 = false, tk1 = false;
#pragma unroll
        for (int p = 0; p < 4; p++) {
            float v = tk0 ? -1e30f : s0;
            int ix = lane;
            float v1 = tk1 ? -1e30f : s1;
            if (v1 > v) { v = v1; ix = lane + 64; }
            for (int off = 32; off; off >>= 1) {
                float ov = __shfl_down(v, off, 64);
                int oi = __shfl_down(ix, off, 64);
                if (ov > v || (ov == v && oi < ix)) { v = ov; ix = oi; }
            }
            v = __shfl(v, 0, 64);
            ix = __shfl(ix, 0, 64);
            if (lane == 0) { tk_val[mb][p] = v; tk_idx[mb][p] = ix; }
            if (ix == lane) tk0 = true;
            if (ix == lane + 64) tk1 = true;
        }
    }
    __syncthreads();
    // ---- pos = sum vals*h[idx]; per_neg = sumh_valid - sum h[idx]
#pragma unroll
    for (int it = 0; it < 2; it++) {
        int task = tid + it * 256;
        if (task < 400) {
            int mb = task / 100, u = task - mb * 100;
            float pos = 0.f, nsum = sumh[it];
#pragma unroll
            for (int p = 0; p < 4; p++) {
                int ix = tk_idx[mb][p];
                float r = out_h[((size_t)(b0 + mb) * Tn + ix) * Hn + u];
                pos += tk_val[mb][p] * r;
                nsum -= r;
            }
            pos_sh[mb][u] = pos;
            per_neg[(size_t)(b0 + mb) * Hn + u] = nsum;
        }
    }
    __syncthreads();
    // ---- projections: out_f = lin(lasth), l_rep = lin(pos)
    if (tid < 48) {
        int which = tid / 24;
        int r = tid - which * 24;
        int mb = r / 6, o = r - mb * 6;
        const float* src = which ? &pos_sh[mb][0] : &lasth_sh[mb][0];
        float acc = linb[o];
        for (int u = 0; u < Hn; u++) acc += src[u] * linW[o * Hn + u];
        d_out[(which ? (Bn * 6) : 0) + (b0 + mb) * 6 + o] = acc;
    }
}

// ---------------- K4: batch cumsum of per_neg (one block per h-dim) ----------
__global__ __launch_bounds__(1024) void k_scan(const float* __restrict__ pn, float* __restrict__ neg) {
    __shared__ float s[Bn];
    int u = blockIdx.x, t = threadIdx.x;
    s[t] = pn[(size_t)t * Hn + u];
    __syncthreads();
    for (int off = 1; off < Bn; off <<= 1) {
        float add = (t >= off) ? s[t - off] : 0.f;
        __syncthreads();
        s[t] += add;
        __syncthreads();
    }
    neg[(size_t)t * Hn + u] = s[t];
}

// ---------------- K5: r_rep = neg @ lin_W^T + lin_b --------------------------
__global__ void k_rrep(const float* __restrict__ neg, const float* __restrict__ linW,
                       const float* __restrict__ linb, float* __restrict__ d_out) {
    int gid = blockIdx.x * 256 + threadIdx.x;
    if (gid < Bn * 6) {
        int b = gid / 6, o = gid - b * 6;
        float acc = linb[o];
        for (int u = 0; u < Hn; u++) acc += neg[(size_t)b * Hn + u] * linW[o * Hn + u];
        d_out[2 * Bn * 6 + gid] = acc;
    }
}

extern "C" void kernel_launch(void* const* d_in, const int* in_sizes, int n_in,
                              void* d_out, int out_size, void* d_ws, size_t ws_size,
                              hipStream_t stream) {
    const int*   word_id = (const int*)d_in[0];
    const int*   sen_len = (const int*)d_in[1];
    const int*   lwid    = (const int*)d_in[2];
    const float* emb     = (const float*)d_in[3];
    const float* W_ih    = (const float*)d_in[4];
    const float* W_hh    = (const float*)d_in[5];
    const float* b_ih    = (const float*)d_in[6];
    const float* b_hh    = (const float*)d_in[7];
    const float* linW    = (const float*)d_in[8];
    const float* linb    = (const float*)d_in[9];
    const float* llW     = (const float*)d_in[10];
    const float* llb     = (const float*)d_in[11];

    char* ws = (char*)d_ws;
    __hip_bfloat16* table = (__hip_bfloat16*)(ws + OFF_TABLE);
    float*          out_h = (float*)(ws + OFF_OUTH);
    __hip_bfloat16* embb  = (__hip_bfloat16*)(ws + OFF_EMBB);  // aliased with out_h
    __hip_bfloat16* wihb  = (__hip_bfloat16*)(ws + OFF_WIHB);
    uint32_t*       wf16  = (uint32_t*)(ws + OFF_WF16);
    float*          lv    = (float*)(ws + OFF_LV);
    float*          pn    = (float*)(ws + OFF_PN);
    float*          neg   = (float*)(ws + OFF_NEG);
    float*          outp  = (float*)d_out;

    k_cvt_emb<<<MPn, 256, 0, stream>>>(emb, embb);
    k_prep<<<(NPn * KPn + 255) / 256, 256, 0, stream>>>(W_ih, W_hh, wihb, wf16);
    k_table<<<MPn / 64, 256, 0, stream>>>(embb, wihb, b_ih, b_hh, table);
    k_label<<<Bn, 128, 0, stream>>>(lwid, emb, llW, llb, lv);
    k_lstm<<<Bn / 4, 256, 0, stream>>>(word_id, sen_len, table, wf16, lv, linW, linb, out_h, pn, outp);
    k_scan<<<Hn, 1024, 0, stream>>>(pn, neg);
    k_rrep<<<(Bn * 6 + 255) / 256, 256, 0, stream>>>(neg, linW, linb, outp);
}

// Round 3
// 522.733 us; speedup vs baseline: 3.0236x; 1.0881x over previous
//
#include <hip/hip_runtime.h>
#include <hip/hip_bf16.h>
#include <cstdint>

// Problem constants
#define Bn   1024
#define Tn   128
#define En   300
#define Hn   100
#define Vn   50000
#define G4n  400   // 4*H
#define KPn  320   // E padded to mult of 32 (MFMA K)
#define MPn  50048 // V padded to mult of 64
#define NPn  448   // 4H padded to mult of 16 (28 n-subtiles)

typedef __bf16 bf16x8 __attribute__((ext_vector_type(8)));
typedef float  f32x4  __attribute__((ext_vector_type(4)));
typedef _Float16 half2v __attribute__((ext_vector_type(2)));

#if __has_builtin(__builtin_amdgcn_fdot2)
__device__ __forceinline__ float DOT2(half2v w, half2v h, float c) {
    return __builtin_amdgcn_fdot2(w, h, c, false);
}
#else
__device__ __forceinline__ float DOT2(half2v w, half2v h, float c) {
    return c + (float)w.x * (float)h.x + (float)w.y * (float)h.y;
}
#endif

// workspace byte offsets
#define OFF_TABLE 0ull          // bf16 [Vn][G4n]           40,000,000
#define OFF_OUTH  40000000ull   // f32  [Bn][Tn][Hn]        52,428,800
#define OFF_EMBB  40000000ull   // bf16 [MPn][KPn] (ALIASED with OUTH; dead before k_lstm)
#define OFF_WIHB  92428800ull   // bf16 [NPn][KPn]             286,720
#define OFF_WF16  92715520ull   // uint [G4n][50] f16-pairs     80,000
#define OFF_LV    92795520ull   // f32  [Bn][Hn]               409,600
#define OFF_PN    93205120ull   // f32  [Bn][Hn]               409,600
#define OFF_NEG   93614720ull   // f32  [Bn][Hn]               409,600

__device__ __forceinline__ float sigf(float x) { return 1.0f / (1.0f + __expf(-x)); }
__device__ __forceinline__ float tanhfast(float x) { return 1.0f - 2.0f / (__expf(2.0f * x) + 1.0f); }

// ---------------- K0a: emb (V,E) f32 -> padded bf16 (MPn,KPn) ----------------
// grid-stride over rows (round-2 used 50048 tiny blocks; dispatch-bound)
__global__ void k_cvt_emb(const float* __restrict__ emb, __hip_bfloat16* __restrict__ embb) {
    for (int m = blockIdx.x; m < MPn; m += gridDim.x) {
        for (int k = threadIdx.x; k < KPn; k += 256) {
            float v = (m < Vn && k < En) ? emb[(size_t)m * En + k] : 0.0f;
            embb[(size_t)m * KPn + k] = __float2bfloat16(v);
        }
    }
}

// ---------------- K0b: W_ih -> padded bf16; W_hh -> f16 k-pairs --------------
__global__ void k_prep(const float* __restrict__ W_ih, const float* __restrict__ W_hh,
                       __hip_bfloat16* __restrict__ wihb, uint32_t* __restrict__ wf16) {
    int idx = blockIdx.x * 256 + threadIdx.x;
    if (idx < NPn * KPn) {
        int n = idx / KPn, k = idx - n * KPn;
        float v = (n < G4n && k < En) ? W_ih[(size_t)n * En + k] : 0.0f;
        wihb[idx] = __float2bfloat16(v);
    }
    if (idx < G4n * 50) {
        int j = idx / 50, kp = idx - j * 50;
        half2v p;
        p.x = (_Float16)W_hh[(size_t)j * Hn + 2 * kp];
        p.y = (_Float16)W_hh[(size_t)j * Hn + 2 * kp + 1];
        wf16[idx] = __builtin_bit_cast(uint32_t, p);
    }
}

// ---------------- K1: table = emb @ W_ih^T + (b_ih+b_hh), bf16 MFMA ----------
__global__ __launch_bounds__(256, 2) void k_table(
    const __hip_bfloat16* __restrict__ embb, const __hip_bfloat16* __restrict__ wihb,
    const float* __restrict__ b_ih, const float* __restrict__ b_hh,
    __hip_bfloat16* __restrict__ table) {
    const int wv = threadIdx.x >> 6, lane = threadIdx.x & 63;
    const int m0 = blockIdx.x * 64 + wv * 16;
    const int row16 = lane & 15, kq = lane >> 4;
    f32x4 acc[28];
#pragma unroll
    for (int i = 0; i < 28; i++) acc[i] = (f32x4){0.f, 0.f, 0.f, 0.f};
    const uint4* A = (const uint4*)embb;
    const uint4* Bm = (const uint4*)wihb;
#pragma unroll
    for (int kk = 0; kk < KPn / 32; kk++) {
        const int ko = kk * 32 + kq * 8;
        uint4 araw = A[((size_t)(m0 + row16) * KPn + ko) >> 3];
        bf16x8 af = __builtin_bit_cast(bf16x8, araw);
#pragma unroll
        for (int ns = 0; ns < 28; ns++) {
            uint4 braw = Bm[((size_t)(ns * 16 + row16) * KPn + ko) >> 3];
            bf16x8 bf = __builtin_bit_cast(bf16x8, braw);
            acc[ns] = __builtin_amdgcn_mfma_f32_16x16x32_bf16(af, bf, acc[ns], 0, 0, 0);
        }
    }
    const int crow = kq * 4;  // C/D: row=(lane>>4)*4+r, col=lane&15
#pragma unroll
    for (int ns = 0; ns < 28; ns++) {
        int n = ns * 16 + row16;
        if (n < G4n) {
            float bias = b_ih[n] + b_hh[n];
#pragma unroll
            for (int r = 0; r < 4; r++) {
                int m = m0 + crow + r;
                if (m < Vn) table[(size_t)m * G4n + n] = __float2bfloat16(acc[ns][r] + bias);
            }
        }
    }
}

// ---------------- K2: label_vec = emb[lid] @ ll_W^T + ll_b (f32) -------------
__global__ void k_label(const int* __restrict__ lwid, const float* __restrict__ emb,
                        const float* __restrict__ llW, const float* __restrict__ llb,
                        float* __restrict__ lv) {
    __shared__ float er[En];
    int b = blockIdx.x;
    int lid = lwid[b];
    for (int k = threadIdx.x; k < En; k += 128) er[k] = emb[(size_t)lid * En + k];
    __syncthreads();
    int h = threadIdx.x;
    if (h < Hn) {
        float acc = llb[h];
        for (int k = 0; k < En; k++) acc += er[k] * llW[(size_t)h * En + k];
        lv[(size_t)b * Hn + h] = acc;
    }
}

// ---------------- K3: fused LSTM, 1 batch elem / block, 1024 blocks ----------
// W_hh in VGPRs (f16 pairs; thread owns gate rows 2*tid, 2*tid+1). h as
// contiguous f16[104] in LDS -> 12 b128 + 1 b64 broadcast reads per step.
// 2 barriers/step; scores on wave 3 off the critical path. 4 blocks/CU target.
__global__ __launch_bounds__(256, 4) void k_lstm(
    const int* __restrict__ word_id, const int* __restrict__ sen_len,
    const __hip_bfloat16* __restrict__ table, const uint32_t* __restrict__ wf16,
    const float* __restrict__ lv, const float* __restrict__ linW,
    const float* __restrict__ linb, float* __restrict__ out_h,
    float* __restrict__ per_neg, float* __restrict__ d_out) {
    __shared__ float g_sh[G4n];        // 1600 B
    __shared__ uint32_t hq[52];        // h as f16[104], pads 100..103 = 0
    __shared__ float lt_sh[Hn];
    __shared__ float scores_sh[Tn];
    __shared__ int   widc[Tn];
    __shared__ float pos_sh[Hn];
    __shared__ float lasth_sh[Hn];
    __shared__ float tk_val[4];
    __shared__ int   tk_idx[4];

    const int tid = threadIdx.x;
    const int b = blockIdx.x;
    const int slen = sen_len[b];
    if (tid < Hn) lt_sh[tid] = lv[(size_t)b * Hn + tid];
    if (tid < 52) hq[tid] = 0u;
    if (tid < Tn) widc[tid] = word_id[b * Tn + tid];

    // ---- W_hh slice -> registers: rows j0, j0+1; 100 contiguous dwords
    const int j0 = tid * 2;
    uint32_t wf[100];
    if (tid < 200) {
        const uint4* wp = (const uint4*)(wf16 + (size_t)j0 * 50);
#pragma unroll
        for (int q = 0; q < 25; q++) {
            uint4 r = wp[q];
            wf[q * 4] = r.x; wf[q * 4 + 1] = r.y; wf[q * 4 + 2] = r.z; wf[q * 4 + 3] = r.w;
        }
    } else {
#pragma unroll
        for (int q = 0; q < 100; q++) wf[q] = 0u;
    }
    __syncthreads();

    const uint16_t* tb16 = (const uint16_t*)table;
    uint32_t xr = 0;
    if (tid < 200) xr = *(const uint32_t*)(tb16 + (size_t)widc[0] * G4n + j0);

    float c_reg = 0.f, sumh = 0.f, lasth_r = 0.f;
    float* outh_b = out_h + (size_t)b * Tn * Hn;

    for (int t = 0; t < Tn; t++) {
        // ---- phase A: gates = W_hh(reg) . h(LDS broadcast) + x(prefetched)
        float a0 = 0.f, a1 = 0.f;
        const uint4* hq4 = (const uint4*)hq;
#pragma unroll
        for (int g = 0; g < 12; g++) {
            uint4 h4 = hq4[g];
            half2v p0 = __builtin_bit_cast(half2v, h4.x);
            half2v p1 = __builtin_bit_cast(half2v, h4.y);
            half2v p2 = __builtin_bit_cast(half2v, h4.z);
            half2v p3 = __builtin_bit_cast(half2v, h4.w);
            a0 = DOT2(__builtin_bit_cast(half2v, wf[g * 4 + 0]), p0, a0);
            a1 = DOT2(__builtin_bit_cast(half2v, wf[50 + g * 4 + 0]), p0, a1);
            a0 = DOT2(__builtin_bit_cast(half2v, wf[g * 4 + 1]), p1, a0);
            a1 = DOT2(__builtin_bit_cast(half2v, wf[50 + g * 4 + 1]), p1, a1);
            a0 = DOT2(__builtin_bit_cast(half2v, wf[g * 4 + 2]), p2, a0);
            a1 = DOT2(__builtin_bit_cast(half2v, wf[50 + g * 4 + 2]), p2, a1);
            a0 = DOT2(__builtin_bit_cast(half2v, wf[g * 4 + 3]), p3, a0);
            a1 = DOT2(__builtin_bit_cast(half2v, wf[50 + g * 4 + 3]), p3, a1);
        }
        {
            uint2 h2 = ((const uint2*)hq)[24];  // pairs 48,49
            half2v pA = __builtin_bit_cast(half2v, h2.x);
            half2v pB = __builtin_bit_cast(half2v, h2.y);
            a0 = DOT2(__builtin_bit_cast(half2v, wf[48]), pA, a0);
            a1 = DOT2(__builtin_bit_cast(half2v, wf[98]), pA, a1);
            a0 = DOT2(__builtin_bit_cast(half2v, wf[49]), pB, a0);
            a1 = DOT2(__builtin_bit_cast(half2v, wf[99]), pB, a1);
        }
        if (tid < 200) {
            float xlo = __uint_as_float(xr << 16);
            float xhi = __uint_as_float(xr & 0xffff0000u);
            float2 gv; gv.x = a0 + xlo; gv.y = a1 + xhi;
            *(float2*)&g_sh[j0] = gv;
            int tn = (t + 1 < Tn) ? t + 1 : t;
            xr = *(const uint32_t*)(tb16 + (size_t)widc[tn] * G4n + j0);
        }
        __syncthreads();  // S1: g_sh ready
        // ---- phase B: elementwise gates -> c,h (lanes 0..99)
        if (tid < Hn) {
            float gi = g_sh[tid], gf = g_sh[tid + 100], gg = g_sh[tid + 200], go = g_sh[tid + 300];
            float c = sigf(gf) * c_reg + sigf(gi) * tanhfast(gg);
            c_reg = c;
            float hh = sigf(go) * tanhfast(c);
            ((_Float16*)hq)[tid] = (_Float16)hh;
            outh_b[t * Hn + tid] = hh;
            if (t < slen) sumh += hh;
            if (t == slen - 1) lasth_r = hh;
        }
        __syncthreads();  // S2: h ready
        // ---- phase C: scores[t] = dot(h, label_vec) on wave 3
        if (tid >= 192) {
            int l = tid - 192;
            const _Float16* hh16 = (const _Float16*)hq;
            float p = (float)hh16[l] * lt_sh[l];
            if (l < 36) p += (float)hh16[l + 64] * lt_sh[l + 64];
            for (int off = 32; off; off >>= 1) p += __shfl_down(p, off, 64);
            if (l == 0) scores_sh[t] = p;
        }
        // no barrier: next B's hq writes are fenced by next S1+S2
    }
    __syncthreads();
    // ---- top-4 on wave 0; tie-break: smaller index
    if (tid < 64) {
        int lane = tid;
        float s0 = (lane < slen) ? scores_sh[lane] : -1e30f;
        float s1 = (lane + 64 < slen) ? scores_sh[lane + 64] : -1e30f;
        bool tk0 = false, tk1 = false;
#pragma unroll
        for (int p = 0; p < 4; p++) {
            float v = tk0 ? -1e30f : s0;
            int ix = lane;
            float v1 = tk1 ? -1e30f : s1;
            if (v1 > v) { v = v1; ix = lane + 64; }
            for (int off = 32; off; off >>= 1) {
                float ov = __shfl_down(v, off, 64);
                int oi = __shfl_down(ix, off, 64);
                if (ov > v || (ov == v && oi < ix)) { v = ov; ix = oi; }
            }
            v = __shfl(v, 0, 64);
            ix = __shfl(ix, 0, 64);
            if (lane == 0) { tk_val[p] = v; tk_idx[p] = ix; }
            if (ix == lane) tk0 = true;
            if (ix == lane + 64) tk1 = true;
        }
    }
    __syncthreads();
    // ---- pos = sum vals*h[idx]; per_neg = sumh_valid - sum h[idx]
    if (tid < Hn) {
        float pos = 0.f, nsum = sumh;
#pragma unroll
        for (int p = 0; p < 4; p++) {
            int ix = tk_idx[p];
            float r = outh_b[ix * Hn + tid];  // this thread wrote these; L1-hot
            pos += tk_val[p] * r;
            nsum -= r;
        }
        pos_sh[tid] = pos;
        lasth_sh[tid] = lasth_r;
        per_neg[(size_t)b * Hn + tid] = nsum;
    }
    __syncthreads();
    // ---- projections: out_f = lin(lasth), l_rep = lin(pos)
    if (tid < 12) {
        int which = tid / 6, o = tid - which * 6;
        const float* src = which ? pos_sh : lasth_sh;
        float acc = linb[o];
        for (int u = 0; u < Hn; u++) acc += src[u] * linW[o * Hn + u];
        d_out[(which ? (Bn * 6) : 0) + b * 6 + o] = acc;
    }
}

// ---------------- K4: batch cumsum of per_neg (one block per h-dim) ----------
__global__ __launch_bounds__(1024) void k_scan(const float* __restrict__ pn, float* __restrict__ neg) {
    __shared__ float s[Bn];
    int u = blockIdx.x, t = threadIdx.x;
    s[t] = pn[(size_t)t * Hn + u];
    __syncthreads();
    for (int off = 1; off < Bn; off <<= 1) {
        float add = (t >= off) ? s[t - off] : 0.f;
        __syncthreads();
        s[t] += add;
        __syncthreads();
    }
    neg[(size_t)t * Hn + u] = s[t];
}

// ---------------- K5: r_rep = neg @ lin_W^T + lin_b --------------------------
__global__ void k_rrep(const float* __restrict__ neg, const float* __restrict__ linW,
                       const float* __restrict__ linb, float* __restrict__ d_out) {
    int gid = blockIdx.x * 256 + threadIdx.x;
    if (gid < Bn * 6) {
        int b = gid / 6, o = gid - b * 6;
        float acc = linb[o];
        for (int u = 0; u < Hn; u++) acc += neg[(size_t)b * Hn + u] * linW[o * Hn + u];
        d_out[2 * Bn * 6 + gid] = acc;
    }
}

extern "C" void kernel_launch(void* const* d_in, const int* in_sizes, int n_in,
                              void* d_out, int out_size, void* d_ws, size_t ws_size,
                              hipStream_t stream) {
    const int*   word_id = (const int*)d_in[0];
    const int*   sen_len = (const int*)d_in[1];
    const int*   lwid    = (const int*)d_in[2];
    const float* emb     = (const float*)d_in[3];
    const float* W_ih    = (const float*)d_in[4];
    const float* W_hh    = (const float*)d_in[5];
    const float* b_ih    = (const float*)d_in[6];
    const float* b_hh    = (const float*)d_in[7];
    const float* linW    = (const float*)d_in[8];
    const float* linb    = (const float*)d_in[9];
    const float* llW     = (const float*)d_in[10];
    const float* llb     = (const float*)d_in[11];

    char* ws = (char*)d_ws;
    __hip_bfloat16* table = (__hip_bfloat16*)(ws + OFF_TABLE);
    float*          out_h = (float*)(ws + OFF_OUTH);
    __hip_bfloat16* embb  = (__hip_bfloat16*)(ws + OFF_EMBB);  // aliased with out_h
    __hip_bfloat16* wihb  = (__hip_bfloat16*)(ws + OFF_WIHB);
    uint32_t*       wf16  = (uint32_t*)(ws + OFF_WF16);
    float*          lv    = (float*)(ws + OFF_LV);
    float*          pn    = (float*)(ws + OFF_PN);
    float*          neg   = (float*)(ws + OFF_NEG);
    float*          outp  = (float*)d_out;

    k_cvt_emb<<<2048, 256, 0, stream>>>(emb, embb);
    k_prep<<<(NPn * KPn + 255) / 256, 256, 0, stream>>>(W_ih, W_hh, wihb, wf16);
    k_table<<<MPn / 64, 256, 0, stream>>>(embb, wihb, b_ih, b_hh, table);
    k_label<<<Bn, 128, 0, stream>>>(lwid, emb, llW, llb, lv);
    k_lstm<<<Bn, 256, 0, stream>>>(word_id, sen_len, table, wf16, lv, linW, linb, out_h, pn, outp);
    k_scan<<<Hn, 1024, 0, stream>>>(pn, neg);
    k_rrep<<<(Bn * 6 + 255) / 256, 256, 0, stream>>>(neg, linW, linb, outp);
}

// Round 4
// 398.534 us; speedup vs baseline: 3.9658x; 1.3116x over previous
//
#include <hip/hip_runtime.h>
#include <hip/hip_bf16.h>
#include <cstdint>

// Problem constants
#define Bn   1024
#define Tn   128
#define En   300
#define Hn   100
#define Vn   50000
#define G4n  400   // 4*H
#define KPn  320   // E padded (k_table MFMA K)
#define MPn  50048 // V padded to mult of 64
#define NPn  448   // 4H padded to mult of 16 (28 n-tiles)
// gate-column PERMUTATION: jp = 4*u + q  <->  j = q*100 + u  (q=gate type i,f,g,o)

typedef __bf16 bf16x8 __attribute__((ext_vector_type(8)));
typedef _Float16 half8 __attribute__((ext_vector_type(8)));
typedef _Float16 half2v __attribute__((ext_vector_type(2)));
typedef float  f32x4  __attribute__((ext_vector_type(4)));

// workspace byte offsets (total 72,807,616 B; <= 94,149,120 known-good)
#define OFF_TABLE 0ull          // f16 [Vn][448] permuted cols   44,843,008
#define OFF_OH16  44843008ull   // f16 [Bn][Tn][Hn]              26,214,400
#define OFF_WIHB  71057408ull   // bf16 [448][320] permuted rows    286,720
#define OFF_WFRAG 71344128ull   // uint4 [28*4*64] W_hh B-frags     114,688
#define OFF_LLWT  71458816ull   // f32 [300][100] llW transposed    120,000
#define OFF_LV    71578816ull   // f32  [Bn][Hn]                    409,600
#define OFF_PN    71988416ull   // f32  [Bn][Hn]                    409,600
#define OFF_NEG   72398016ull   // f32  [Bn][Hn]                    409,600

__device__ __forceinline__ float sigf(float x) { return 1.0f / (1.0f + __expf(-x)); }
__device__ __forceinline__ float tanhfast(float x) { return 1.0f - 2.0f / (__expf(2.0f * x) + 1.0f); }

// -------- K0: W_ih -> permuted bf16; W_hh -> MFMA B-fragments (f16);
//          llW -> transposed f32 --------------------------------------------
__global__ void k_prep(const float* __restrict__ W_ih, const float* __restrict__ W_hh,
                       const float* __restrict__ llW,
                       __hip_bfloat16* __restrict__ wihb, uint4* __restrict__ wfrag,
                       float* __restrict__ llwt) {
    int idx = blockIdx.x * 256 + threadIdx.x;
    if (idx < NPn * KPn) {  // wihb[np][k] = W_ih[perm(np)][k]
        int np = idx / KPn, k = idx - np * KPn;
        int q = np & 3, u = np >> 2;
        float v = (u < Hn && k < En) ? W_ih[(size_t)(q * Hn + u) * En + k] : 0.0f;
        wihb[idx] = __float2bfloat16(v);
    }
    if (idx < 28 * 4 * 64) {  // B-fragment: lane holds B[n=nt*16+(l&15)][k=kc*32+(l>>4)*8+j]
        int lane = idx & 63, tk = idx >> 6;
        int nt = tk >> 2, kc = tk & 3;
        int n = nt * 16 + (lane & 15);
        int k0 = kc * 32 + (lane >> 4) * 8;
        int q = n & 3, u = n >> 2;
        union { _Float16 h[8]; uint4 v; } pk;
#pragma unroll
        for (int j8 = 0; j8 < 8; j8++) {
            int k = k0 + j8;
            float v = (u < Hn && k < Hn) ? W_hh[(size_t)(q * Hn + u) * Hn + k] : 0.0f;
            pk.h[j8] = (_Float16)v;
        }
        wfrag[idx] = pk.v;
    }
    if (idx < En * Hn) {  // llwt[k][h] = llW[h][k]
        int k = idx / Hn, h = idx - k * Hn;
        llwt[idx] = llW[(size_t)h * En + k];
    }
}

// -------- K1: table[v][jp] = (emb @ W_ih^T + b)[v][perm(jp)], f16, MFMA bf16 -
// A read directly from f32 emb (converted in-register). 782 blocks.
__global__ __launch_bounds__(256, 2) void k_table(
    const float* __restrict__ emb, const __hip_bfloat16* __restrict__ wihb,
    const float* __restrict__ b_ih, const float* __restrict__ b_hh,
    _Float16* __restrict__ table) {
    const int wv = threadIdx.x >> 6, lane = threadIdx.x & 63;
    const int m0 = blockIdx.x * 64 + wv * 16;
    const int row16 = lane & 15, kq = lane >> 4;
    f32x4 acc[28];
#pragma unroll
    for (int i = 0; i < 28; i++) acc[i] = (f32x4){0.f, 0.f, 0.f, 0.f};
    const int row = m0 + row16;
    const float* ar = emb + (size_t)(row < Vn ? row : Vn - 1) * En;
    const uint4* Bm = (const uint4*)wihb;
#pragma unroll
    for (int kk = 0; kk < 10; kk++) {
        const int ko = kk * 32 + kq * 8;
        bf16x8 af;
        if (ko + 8 <= En) {
            float4 p = *(const float4*)(ar + ko);
            float4 qv = *(const float4*)(ar + ko + 4);
            af[0] = (__bf16)p.x;  af[1] = (__bf16)p.y;  af[2] = (__bf16)p.z;  af[3] = (__bf16)p.w;
            af[4] = (__bf16)qv.x; af[5] = (__bf16)qv.y; af[6] = (__bf16)qv.z; af[7] = (__bf16)qv.w;
        } else if (ko < En) {  // ko = 296: 4 valid
            float4 p = *(const float4*)(ar + ko);
            af[0] = (__bf16)p.x; af[1] = (__bf16)p.y; af[2] = (__bf16)p.z; af[3] = (__bf16)p.w;
            af[4] = (__bf16)0.f; af[5] = (__bf16)0.f; af[6] = (__bf16)0.f; af[7] = (__bf16)0.f;
        } else {
#pragma unroll
            for (int i = 0; i < 8; i++) af[i] = (__bf16)0.f;
        }
#pragma unroll
        for (int ns = 0; ns < 28; ns++) {
            bf16x8 bf = __builtin_bit_cast(bf16x8, Bm[((size_t)(ns * 16 + row16) * KPn + ko) >> 3]);
            acc[ns] = __builtin_amdgcn_mfma_f32_16x16x32_bf16(af, bf, acc[ns], 0, 0, 0);
        }
    }
    const int crow = kq * 4;  // C/D: row=(lane>>4)*4+r, col=lane&15
#pragma unroll
    for (int ns = 0; ns < 28; ns++) {
        int n = ns * 16 + row16;
        int q = n & 3, u = n >> 2;
        if (u < Hn) {
            int j = q * Hn + u;
            float bias = b_ih[j] + b_hh[j];
#pragma unroll
            for (int r = 0; r < 4; r++) {
                int m = m0 + crow + r;
                if (m < Vn) table[(size_t)m * NPn + n] = (_Float16)(acc[ns][r] + bias);
            }
        }
    }
}

// -------- K2: label_vec = emb[lid] @ ll_W^T + ll_b (f32, coalesced llwt) -----
__global__ void k_label(const int* __restrict__ lwid, const float* __restrict__ emb,
                        const float* __restrict__ llwt, const float* __restrict__ llb,
                        float* __restrict__ lv) {
    __shared__ float er[En];
    int b = blockIdx.x;
    int lid = lwid[b];
    for (int k = threadIdx.x; k < En; k += 128) er[k] = emb[(size_t)lid * En + k];
    __syncthreads();
    int h = threadIdx.x;
    if (h < Hn) {
        float acc = llb[h];
        for (int k = 0; k < En; k++) acc += er[k] * llwt[k * Hn + h];
        lv[(size_t)b * Hn + h] = acc;
    }
}

// -------- K3: fused LSTM, 2 batch/block, MFMA f16 recurrence -----------------
// W_hh as persistent B-fragments in VGPRs (28 frags/wave = 112 VGPR).
// Per step: 4 A-frag LDS reads + 28 MFMA/wave + 2 barriers.
__global__ __launch_bounds__(256, 2) void k_lstm(
    const int* __restrict__ word_id, const int* __restrict__ sen_len,
    const _Float16* __restrict__ table, const uint4* __restrict__ wfrag,
    const float* __restrict__ lv, const float* __restrict__ linW,
    const float* __restrict__ linb, _Float16* __restrict__ oh16,
    float* __restrict__ per_neg, float* __restrict__ d_out) {
    __shared__ float    g_sh[2][NPn];      // gates (permuted), f32
    __shared__ _Float16 h_cur[3][128];     // rows 0,1 = batch h (cols>=100 zero); row 2 = zeros
    __shared__ float    lt_sh[2][Hn];
    __shared__ float    scores_sh[2][Tn];
    __shared__ int      widc[2][Tn];
    __shared__ float    pos_sh[2][Hn];
    __shared__ float    lasth_sh[2][Hn];
    __shared__ float    tk_val[2][4];
    __shared__ int      tk_idx[2][4];

    const int tid = threadIdx.x;
    const int w = tid >> 6, l = tid & 63;
    const int c16 = l & 15, quad = l >> 4;
    const int b0 = blockIdx.x * 2;

    // init LDS
    if (tid < 192) ((uint32_t*)h_cur)[tid] = 0u;  // 3*128 halves
    if (tid < 200) {
        int mb = (tid >= Hn), u = tid - mb * Hn;
        lt_sh[mb][u] = lv[(size_t)(b0 + mb) * Hn + u];
    }
    { int mb = tid >> 7, t = tid & 127; widc[mb][t] = word_id[(b0 + mb) * Tn + t]; }

    // persistent W_hh B-fragments
    half8 bfr[7][4];
#pragma unroll
    for (int n7 = 0; n7 < 7; n7++)
#pragma unroll
        for (int kc = 0; kc < 4; kc++)
            bfr[n7][kc] = __builtin_bit_cast(half8, wfrag[((w * 7 + n7) * 4 + kc) * 64 + l]);

    int slen[2];
    slen[0] = sen_len[b0]; slen[1] = sen_len[b0 + 1];
    __syncthreads();

    // phase-B thread identity + x prefetch for t=0
    const int mb = (tid >= Hn) ? 1 : 0;
    const int u = tid - mb * Hn;           // valid when tid<200
    uint2 xq = {0, 0};
    if (tid < 200) xq = *(const uint2*)(table + (size_t)widc[mb][0] * NPn + u * 4);

    float c_reg = 0.f, sumh = 0.f, lasth = 0.f;
    _Float16* ohb_w = oh16 + (size_t)(b0 + mb) * Tn * Hn;

    for (int t = 0; t < Tn; t++) {
        // ---- phase A: gates(mfma) = h . W_hh^T
        f32x4 acc[7];
#pragma unroll
        for (int n7 = 0; n7 < 7; n7++) acc[n7] = (f32x4){0.f, 0.f, 0.f, 0.f};
        const _Float16* ap = h_cur[(t > 0 && c16 < 2) ? c16 : 2];
#pragma unroll
        for (int kc = 0; kc < 4; kc++) {
            half8 af = *(const half8*)(ap + kc * 32 + quad * 8);
#pragma unroll
            for (int n7 = 0; n7 < 7; n7++)
                acc[n7] = __builtin_amdgcn_mfma_f32_16x16x32_f16(af, bfr[n7][kc], acc[n7], 0, 0, 0);
        }
        if (l < 16) {  // C rows 0,1 live in quad 0, r=0,1
#pragma unroll
            for (int n7 = 0; n7 < 7; n7++) {
                int n = (w * 7 + n7) * 16 + l;
                g_sh[0][n] = acc[n7][0];
                g_sh[1][n] = acc[n7][1];
            }
        }
        __syncthreads();  // S1: gates ready
        // ---- phase B: + x, nonlinearity, h update (threads 0..199)
        if (tid < 200) {
            float4 g4 = *(const float4*)&g_sh[mb][u * 4];
            half2v x01 = __builtin_bit_cast(half2v, xq.x);
            half2v x23 = __builtin_bit_cast(half2v, xq.y);
            float gi = g4.x + (float)x01.x;
            float gf = g4.y + (float)x01.y;
            float gg = g4.z + (float)x23.x;
            float go = g4.w + (float)x23.y;
            float c = sigf(gf) * c_reg + sigf(gi) * tanhfast(gg);
            c_reg = c;
            float hh = sigf(go) * tanhfast(c);
            h_cur[mb][u] = (_Float16)hh;
            ohb_w[t * Hn + u] = (_Float16)hh;
            if (t < slen[mb]) sumh += hh;
            if (t == slen[mb] - 1) lasth = hh;
            int tn = (t + 1 < Tn) ? t + 1 : t;
            xq = *(const uint2*)(table + (size_t)widc[mb][tn] * NPn + u * 4);
        }
        __syncthreads();  // S2: h ready
        // ---- phase C: scores on wave 3
        if (w == 3) {
            int smb = l >> 5, ll = l & 31;
            float p = (float)h_cur[smb][ll] * lt_sh[smb][ll]
                    + (float)h_cur[smb][ll + 32] * lt_sh[smb][ll + 32]
                    + (float)h_cur[smb][ll + 64] * lt_sh[smb][ll + 64];
            if (ll < 4) p += (float)h_cur[smb][ll + 96] * lt_sh[smb][ll + 96];
            for (int off = 16; off; off >>= 1) p += __shfl_down(p, off, 32);
            if (ll == 0) scores_sh[smb][t] = p;
        }
        // no barrier: wave3's reads drain before it passes next S1
    }
    __syncthreads();
    // ---- top-4: wave 0 -> mb 0, wave 1 -> mb 1; tie-break smaller index
    if (w < 2) {
        int kmb = w, lane = l;
        float s0 = (lane < slen[kmb]) ? scores_sh[kmb][lane] : -1e30f;
        float s1 = (lane + 64 < slen[kmb]) ? scores_sh[kmb][lane + 64] : -1e30f;
        bool tk0 = false, tk1 = false;
#pragma unroll
        for (int p = 0; p < 4; p++) {
            float v = tk0 ? -1e30f : s0;
            int ix = lane;
            float v1 = tk1 ? -1e30f : s1;
            if (v1 > v) { v = v1; ix = lane + 64; }
            for (int off = 32; off; off >>= 1) {
                float ov = __shfl_down(v, off, 64);
                int oi = __shfl_down(ix, off, 64);
                if (ov > v || (ov == v && oi < ix)) { v = ov; ix = oi; }
            }
            v = __shfl(v, 0, 64);
            ix = __shfl(ix, 0, 64);
            if (lane == 0) { tk_val[kmb][p] = v; tk_idx[kmb][p] = ix; }
            if (ix == lane) tk0 = true;
            if (ix == lane + 64) tk1 = true;
        }
    }
    __syncthreads();
    // ---- pos / per_neg / lasth
    if (tid < 200) {
        float pos = 0.f, nsum = sumh;
#pragma unroll
        for (int p = 0; p < 4; p++) {
            int ix = tk_idx[mb][p];
            float r = (float)ohb_w[ix * Hn + u];
            pos += tk_val[mb][p] * r;
            nsum -= r;
        }
        pos_sh[mb][u] = pos;
        lasth_sh[mb][u] = lasth;
        per_neg[(size_t)(b0 + mb) * Hn + u] = nsum;
    }
    __syncthreads();
    // ---- projections: out_f = lin(lasth), l_rep = lin(pos)
    if (tid < 24) {
        int which = tid / 12, r = tid - which * 12;
        int pmb = r / 6, o = r - pmb * 6;
        const float* src = which ? &pos_sh[pmb][0] : &lasth_sh[pmb][0];
        float acc = linb[o];
        for (int uu = 0; uu < Hn; uu++) acc += src[uu] * linW[o * Hn + uu];
        d_out[(which ? (Bn * 6) : 0) + (b0 + pmb) * 6 + o] = acc;
    }
}

// -------- K4: batch cumsum of per_neg (one block per h-dim) ------------------
__global__ __launch_bounds__(1024) void k_scan(const float* __restrict__ pn, float* __restrict__ neg) {
    __shared__ float s[Bn];
    int u = blockIdx.x, t = threadIdx.x;
    s[t] = pn[(size_t)t * Hn + u];
    __syncthreads();
    for (int off = 1; off < Bn; off <<= 1) {
        float add = (t >= off) ? s[t - off] : 0.f;
        __syncthreads();
        s[t] += add;
        __syncthreads();
    }
    neg[(size_t)t * Hn + u] = s[t];
}

// -------- K5: r_rep = neg @ lin_W^T + lin_b ----------------------------------
__global__ void k_rrep(const float* __restrict__ neg, const float* __restrict__ linW,
                       const float* __restrict__ linb, float* __restrict__ d_out) {
    int gid = blockIdx.x * 256 + threadIdx.x;
    if (gid < Bn * 6) {
        int b = gid / 6, o = gid - b * 6;
        float acc = linb[o];
        for (int u = 0; u < Hn; u++) acc += neg[(size_t)b * Hn + u] * linW[o * Hn + u];
        d_out[2 * Bn * 6 + gid] = acc;
    }
}

extern "C" void kernel_launch(void* const* d_in, const int* in_sizes, int n_in,
                              void* d_out, int out_size, void* d_ws, size_t ws_size,
                              hipStream_t stream) {
    const int*   word_id = (const int*)d_in[0];
    const int*   sen_len = (const int*)d_in[1];
    const int*   lwid    = (const int*)d_in[2];
    const float* emb     = (const float*)d_in[3];
    const float* W_ih    = (const float*)d_in[4];
    const float* W_hh    = (const float*)d_in[5];
    const float* b_ih    = (const float*)d_in[6];
    const float* b_hh    = (const float*)d_in[7];
    const float* linW    = (const float*)d_in[8];
    const float* linb    = (const float*)d_in[9];
    const float* llW     = (const float*)d_in[10];
    const float* llb     = (const float*)d_in[11];

    char* ws = (char*)d_ws;
    _Float16*       table = (_Float16*)(ws + OFF_TABLE);
    _Float16*       oh16  = (_Float16*)(ws + OFF_OH16);
    __hip_bfloat16* wihb  = (__hip_bfloat16*)(ws + OFF_WIHB);
    uint4*          wfrag = (uint4*)(ws + OFF_WFRAG);
    float*          llwt  = (float*)(ws + OFF_LLWT);
    float*          lvp   = (float*)(ws + OFF_LV);
    float*          pn    = (float*)(ws + OFF_PN);
    float*          neg   = (float*)(ws + OFF_NEG);
    float*          outp  = (float*)d_out;

    k_prep<<<(NPn * KPn + 255) / 256, 256, 0, stream>>>(W_ih, W_hh, llW, wihb, wfrag, llwt);
    k_table<<<MPn / 64, 256, 0, stream>>>(emb, wihb, b_ih, b_hh, table);
    k_label<<<Bn, 128, 0, stream>>>(lwid, emb, llwt, llb, lvp);
    k_lstm<<<Bn / 2, 256, 0, stream>>>(word_id, sen_len, table, wfrag, lvp, linW, linb, oh16, pn, outp);
    k_scan<<<Hn, 1024, 0, stream>>>(pn, neg);
    k_rrep<<<(Bn * 6 + 255) / 256, 256, 0, stream>>>(neg, linW, linb, outp);
}

// Round 5
// 309.317 us; speedup vs baseline: 5.1097x; 1.2884x over previous
//
#include <hip/hip_runtime.h>
#include <hip/hip_bf16.h>
#include <cstdint>

// Problem constants
#define Bn   1024
#define Tn   128
#define En   300
#define Hn   100
#define Vn   50000
#define G4n  400   // 4*H
#define MPn  50048 // V padded to mult of 64
#define NPn  448   // 4H padded to mult of 16 (28 n-tiles)
// gate-column PERMUTATION: jp = 4*u + q  <->  j = q*100 + u  (q = gate i,f,g,o)

typedef __bf16 bf16x8 __attribute__((ext_vector_type(8)));
typedef _Float16 half8 __attribute__((ext_vector_type(8)));
typedef _Float16 half2v __attribute__((ext_vector_type(2)));
typedef float  f32x4  __attribute__((ext_vector_type(4)));

// workspace byte offsets (total 72,764,608 B; <= 94 MB known-good)
#define OFF_TABLE  0ull         // f16 [Vn][448] permuted cols   44,800,000
#define OFF_OH16   44800000ull  // f16 [Bn][Tn][Hn]              26,214,400
#define OFF_WFRAG  71014400ull  // uint4 [28*4*64] W_hh B-frags     114,688
#define OFF_WFRAGB 71129088ull  // uint4 [10*28*64] W_ih B-frags    286,720
#define OFF_LLWT   71415808ull  // f32 [300][100] llW transposed    120,000
#define OFF_LV     71535808ull  // f32 [Bn][Hn]                     409,600
#define OFF_PN     71945408ull  // f32 [Bn][Hn]                     409,600
#define OFF_NEG    72355008ull  // f32 [Bn][Hn]                     409,600

__device__ __forceinline__ float sigf(float x) { return 1.0f / (1.0f + __expf(-x)); }
__device__ __forceinline__ float tanhfast(float x) { return 1.0f - 2.0f / (__expf(2.0f * x) + 1.0f); }

// -------- K0: W_hh -> f16 B-frags; W_ih -> bf16 B-frags; llW -> transposed ---
__global__ void k_prep(const float* __restrict__ W_ih, const float* __restrict__ W_hh,
                       const float* __restrict__ llW,
                       uint4* __restrict__ wfrag, uint4* __restrict__ wfragB,
                       float* __restrict__ llwt) {
    int idx = blockIdx.x * 256 + threadIdx.x;
    if (idx < 28 * 4 * 64) {  // W_hh frag: lane holds B[n=nt*16+(l&15)][k=kc*32+(l>>4)*8+j]
        int lane = idx & 63, tk = idx >> 6;
        int nt = tk >> 2, kc = tk & 3;
        int n = nt * 16 + (lane & 15);
        int k0 = kc * 32 + (lane >> 4) * 8;
        int q = n & 3, u = n >> 2;
        union { _Float16 h[8]; uint4 v; } pk;
#pragma unroll
        for (int j = 0; j < 8; j++) {
            int k = k0 + j;
            pk.h[j] = (_Float16)((u < Hn && k < Hn) ? W_hh[(size_t)(q * Hn + u) * Hn + k] : 0.0f);
        }
        wfrag[idx] = pk.v;
    }
    if (idx < 10 * 28 * 64) {  // W_ih frag (bf16): kc-major
        int lane = idx & 63, tk = idx >> 6;
        int kc = tk / 28, nsg = tk - kc * 28;
        int n = nsg * 16 + (lane & 15);
        int k0 = kc * 32 + (lane >> 4) * 8;
        int q = n & 3, u = n >> 2;
        union { __bf16 h[8]; uint4 v; } pk;
#pragma unroll
        for (int j = 0; j < 8; j++) {
            int k = k0 + j;
            pk.h[j] = (__bf16)((u < Hn && k < En) ? W_ih[(size_t)(q * Hn + u) * En + k] : 0.0f);
        }
        wfragB[idx] = pk.v;
    }
    if (idx < En * Hn) {  // llwt[k][h] = llW[h][k]
        int k = idx / Hn, h = idx - k * Hn;
        llwt[idx] = llW[(size_t)h * En + k];
    }
}

// -------- K1: table = emb @ W_ih^T + b (permuted cols, f16 out) --------------
// A staged once in LDS (bf16, padded stride 328); B-frags streamed coalesced
// from wfragB with register double-buffer. Block: 64 M-rows x 224 N-half.
__global__ __launch_bounds__(256, 2) void k_table(
    const float* __restrict__ emb, const uint4* __restrict__ wfragB,
    const float* __restrict__ b_ih, const float* __restrict__ b_hh,
    _Float16* __restrict__ table) {
    __shared__ __bf16 a_sh[64][328];   // 41,984 B (stride 328: rows offset 4 banks)
    const int tid = threadIdx.x;
    const int mt = blockIdx.x >> 1, nh = blockIdx.x & 1;

    // stage A: 64 rows x 320 cols (zeros past 300)
#pragma unroll
    for (int it = 0; it < 5; it++) {
        int x = it * 256 + tid;            // 0..1279
        int row = x / 20, seg = x - row * 20;
        int gr = mt * 64 + row;
        const float* ar = emb + (size_t)(gr < Vn ? gr : Vn - 1) * En;
        int c0 = seg * 16;
        union { __bf16 h[16]; bf16x8 v[2]; } pk;
#pragma unroll
        for (int g = 0; g < 4; g++) {
            int c = c0 + g * 4;
            if (c + 4 <= En) {
                float4 f = *(const float4*)(ar + c);
                pk.h[g * 4 + 0] = (__bf16)f.x; pk.h[g * 4 + 1] = (__bf16)f.y;
                pk.h[g * 4 + 2] = (__bf16)f.z; pk.h[g * 4 + 3] = (__bf16)f.w;
            } else {
                pk.h[g * 4 + 0] = (__bf16)0.f; pk.h[g * 4 + 1] = (__bf16)0.f;
                pk.h[g * 4 + 2] = (__bf16)0.f; pk.h[g * 4 + 3] = (__bf16)0.f;
            }
        }
        *(bf16x8*)&a_sh[row][c0] = pk.v[0];
        *(bf16x8*)&a_sh[row][c0 + 8] = pk.v[1];
    }
    __syncthreads();

    const int wv = tid >> 6, l = tid & 63;
    const int c16 = l & 15, quad = l >> 4;
    f32x4 acc[14];
#pragma unroll
    for (int i = 0; i < 14; i++) acc[i] = (f32x4){0.f, 0.f, 0.f, 0.f};

    uint4 bcur[14];
#pragma unroll
    for (int ns = 0; ns < 14; ns++) bcur[ns] = wfragB[((0 * 28 + nh * 14 + ns) << 6) + l];

    for (int kc = 0; kc < 10; kc++) {
        uint4 bnxt[14];
        if (kc < 9) {
#pragma unroll
            for (int ns = 0; ns < 14; ns++) bnxt[ns] = wfragB[(((kc + 1) * 28 + nh * 14 + ns) << 6) + l];
        }
        bf16x8 af = *(const bf16x8*)&a_sh[wv * 16 + c16][kc * 32 + quad * 8];
#pragma unroll
        for (int ns = 0; ns < 14; ns++)
            acc[ns] = __builtin_amdgcn_mfma_f32_16x16x32_bf16(af, __builtin_bit_cast(bf16x8, bcur[ns]), acc[ns], 0, 0, 0);
        if (kc < 9) {
#pragma unroll
            for (int ns = 0; ns < 14; ns++) bcur[ns] = bnxt[ns];
        }
    }
    // epilogue: C/D row = quad*4+r, col = c16
#pragma unroll
    for (int ns = 0; ns < 14; ns++) {
        int n = (nh * 14 + ns) * 16 + c16;
        int q = n & 3, u = n >> 2;
        if (u < Hn) {
            int j = q * Hn + u;
            float bias = b_ih[j] + b_hh[j];
#pragma unroll
            for (int r = 0; r < 4; r++) {
                int m = mt * 64 + wv * 16 + quad * 4 + r;
                if (m < Vn) table[(size_t)m * NPn + n] = (_Float16)(acc[ns][r] + bias);
            }
        }
    }
}

// -------- K2: label_vec = emb[lid] @ ll_W^T + ll_b (2-way K split) -----------
__global__ void k_label(const int* __restrict__ lwid, const float* __restrict__ emb,
                        const float* __restrict__ llwt, const float* __restrict__ llb,
                        float* __restrict__ lv) {
    __shared__ float er[En];
    __shared__ float part[Hn];
    int b = blockIdx.x;
    int lid = lwid[b];
    for (int k = threadIdx.x; k < En; k += 256) er[k] = emb[(size_t)lid * En + k];
    __syncthreads();
    int h = threadIdx.x & 127, half = threadIdx.x >> 7;
    float acc = 0.f;
    if (h < Hn) {
        int k0 = half * 150, k1 = k0 + 150;
        for (int k = k0; k < k1; k++) acc += er[k] * llwt[k * Hn + h];
        if (half == 1) part[h] = acc;
    }
    __syncthreads();
    if (h < Hn && half == 0) lv[(size_t)b * Hn + h] = acc + part[h] + llb[h];
}

// -------- K3: fused LSTM, 2 batch/block, MFMA f16, ONE barrier/step ----------
// Wave w owns u in [28w, 28w+28) x mb in {0,1} (lane = 2*u_loc + mb).
// Gates staged wave-locally (stride-5, conflict-free, no barrier); h double-
// buffered in LDS (padded rows). Scores reduced in-wave to per-wave partials.
__global__ __launch_bounds__(256, 2) void k_lstm(
    const int* __restrict__ word_id, const int* __restrict__ sen_len,
    const _Float16* __restrict__ table, const uint4* __restrict__ wfrag,
    const float* __restrict__ lv, const float* __restrict__ linW,
    const float* __restrict__ linb, _Float16* __restrict__ oh16,
    float* __restrict__ per_neg, float* __restrict__ d_out) {
    __shared__ float    gbufs[4][280];     // per wave [2 mb][140] stride-5
    __shared__ _Float16 h_cur[2][2][136];  // [parity][mb][136], cols>=100 zero
    __shared__ float    lt_sh[2][Hn];
    __shared__ float    spw[2][Tn][4];     // per-wave score partials
    __shared__ int      widc[2][Tn];
    __shared__ float    pos_sh[2][Hn];
    __shared__ float    lasth_sh[2][Hn];
    __shared__ float    tk_val[2][4];
    __shared__ int      tk_idx[2][4];

    const int tid = threadIdx.x;
    const int w = tid >> 6, l = tid & 63;
    const int c16 = l & 15, quad = l >> 4;
    const int b0 = blockIdx.x * 2;

    // init
    for (int i = tid; i < 272; i += 256) ((uint32_t*)h_cur)[i] = 0u;  // both parities + pads
    if (tid < 200) {
        int imb = (tid >= Hn), iu = tid - imb * Hn;
        lt_sh[imb][iu] = lv[(size_t)(b0 + imb) * Hn + iu];
    }
    { int imb = tid >> 7, it = tid & 127; widc[imb][it] = word_id[(b0 + imb) * Tn + it]; }

    // persistent W_hh B-fragments
    half8 bfr[7][4];
#pragma unroll
    for (int n7 = 0; n7 < 7; n7++)
#pragma unroll
        for (int kc = 0; kc < 4; kc++)
            bfr[n7][kc] = __builtin_bit_cast(half8, wfrag[((w * 7 + n7) * 4 + kc) * 64 + l]);

    // lane work identity
    const int u_loc = l >> 1, mb = l & 1;
    const int u = w * 28 + u_loc;
    const bool act = (l < 56) && (u < Hn);
    const int myslen = act ? sen_len[b0 + mb] : 0;
    float* gb = &gbufs[w][0];

    __syncthreads();

    uint2 xq = {0, 0};
    if (act) xq = *(const uint2*)(table + (size_t)widc[mb][0] * NPn + u * 4);

    float c_reg = 0.f, sumh = 0.f, lasth = 0.f;
    _Float16* ohb_w = oh16 + (size_t)(b0 + mb) * Tn * Hn;

    for (int t = 0; t < Tn; t++) {
        // ---- MFMA: gates = h . W_hh^T (A from parity t&1)
        const _Float16* hp = &h_cur[t & 1][0][0];
        f32x4 acc[7];
#pragma unroll
        for (int n7 = 0; n7 < 7; n7++) acc[n7] = (f32x4){0.f, 0.f, 0.f, 0.f};
#pragma unroll
        for (int kc = 0; kc < 4; kc++) {
            half8 af = *(const half8*)(hp + (c16 & 1) * 136 + kc * 32 + quad * 8);
#pragma unroll
            for (int n7 = 0; n7 < 7; n7++)
                acc[n7] = __builtin_amdgcn_mfma_f32_16x16x32_f16(af, bfr[n7][kc], acc[n7], 0, 0, 0);
        }
        // ---- wave-local gate stage (C rows 0,1 live in quad 0)
        if (l < 16) {
#pragma unroll
            for (int n7 = 0; n7 < 7; n7++) {
                int nl = n7 * 16 + l;
                int adr = (nl >> 2) * 5 + (nl & 3);
                gb[adr] = acc[n7][0];
                gb[140 + adr] = acc[n7][1];
            }
        }
        // wave-synchronous: lgkmcnt ordering within wave, no barrier
        float p = 0.f;
        if (act) {
            int base = mb * 140 + u_loc * 5;
            half2v x01 = __builtin_bit_cast(half2v, xq.x);
            half2v x23 = __builtin_bit_cast(half2v, xq.y);
            float gi = gb[base] + (float)x01.x;
            float gf = gb[base + 1] + (float)x01.y;
            float gg = gb[base + 2] + (float)x23.x;
            float go = gb[base + 3] + (float)x23.y;
            float c = sigf(gf) * c_reg + sigf(gi) * tanhfast(gg);
            c_reg = c;
            float hh = sigf(go) * tanhfast(c);
            h_cur[(t + 1) & 1][mb][u] = (_Float16)hh;
            ohb_w[t * Hn + u] = (_Float16)hh;
            if (t < myslen) sumh += hh;
            if (t == myslen - 1) lasth = hh;
            p = hh * lt_sh[mb][u];
            int tn = (t + 1 < Tn) ? t + 1 : t;
            xq = *(const uint2*)(table + (size_t)widc[mb][tn] * NPn + u * 4);
        }
        // ---- in-wave score reduce (parity-preserving strides)
        p += __shfl_down(p, 32, 64);
        p += __shfl_down(p, 16, 64);
        p += __shfl_down(p, 8, 64);
        p += __shfl_down(p, 4, 64);
        p += __shfl_down(p, 2, 64);
        if (l < 2) spw[l][t][w] = p;
        __syncthreads();  // h(t+1) + spw visible to all waves
    }
    // ---- top-4: wave 0 -> mb 0, wave 1 -> mb 1; tie-break smaller index
    if (w < 2) {
        int kmb = w, lane = l;
        int sl = sen_len[b0 + kmb];
        float4 p0 = *(const float4*)&spw[kmb][lane][0];
        float4 p1 = *(const float4*)&spw[kmb][lane + 64][0];
        float s0 = (lane < sl) ? (p0.x + p0.y + p0.z + p0.w) : -1e30f;
        float s1 = (lane + 64 < sl) ? (p1.x + p1.y + p1.z + p1.w) : -1e30f;
        bool tk0 = false, tk1 = false;
#pragma unroll
        for (int p4 = 0; p4 < 4; p4++) {
            float v = tk0 ? -1e30f : s0;
            int ix = lane;
            float v1 = tk1 ? -1e30f : s1;
            if (v1 > v) { v = v1; ix = lane + 64; }
            for (int off = 32; off; off >>= 1) {
                float ov = __shfl_down(v, off, 64);
                int oi = __shfl_down(ix, off, 64);
                if (ov > v || (ov == v && oi < ix)) { v = ov; ix = oi; }
            }
            v = __shfl(v, 0, 64);
            ix = __shfl(ix, 0, 64);
            if (lane == 0) { tk_val[kmb][p4] = v; tk_idx[kmb][p4] = ix; }
            if (ix == lane) tk0 = true;
            if (ix == lane + 64) tk1 = true;
        }
    }
    __syncthreads();
    // ---- pos / per_neg / lasth (lane ownership)
    if (act) {
        float pos = 0.f, nsum = sumh;
#pragma unroll
        for (int p4 = 0; p4 < 4; p4++) {
            int ix = tk_idx[mb][p4];
            float r = (float)ohb_w[ix * Hn + u];
            pos += tk_val[mb][p4] * r;
            nsum -= r;
        }
        pos_sh[mb][u] = pos;
        lasth_sh[mb][u] = lasth;
        per_neg[(size_t)(b0 + mb) * Hn + u] = nsum;
    }
    __syncthreads();
    // ---- projections: out_f = lin(lasth), l_rep = lin(pos)
    if (tid < 24) {
        int which = tid / 12, r = tid - which * 12;
        int pmb = r / 6, o = r - pmb * 6;
        const float* src = which ? &pos_sh[pmb][0] : &lasth_sh[pmb][0];
        float acc2 = linb[o];
        for (int uu = 0; uu < Hn; uu++) acc2 += src[uu] * linW[o * Hn + uu];
        d_out[(which ? (Bn * 6) : 0) + (b0 + pmb) * 6 + o] = acc2;
    }
}

// -------- K4: batch cumsum of per_neg (wave-shuffle scan, 2 barriers) --------
__global__ __launch_bounds__(1024) void k_scan(const float* __restrict__ pn, float* __restrict__ neg) {
    __shared__ float wsum[16];
    __shared__ float wpre[16];
    int u = blockIdx.x, t = threadIdx.x;
    int lane = t & 63, wv = t >> 6;
    float v = pn[(size_t)t * Hn + u];
#pragma unroll
    for (int off = 1; off < 64; off <<= 1) {
        float o = __shfl_up(v, off, 64);
        if (lane >= off) v += o;
    }
    if (lane == 63) wsum[wv] = v;
    __syncthreads();
    if (t < 16) {
        float s = wsum[t];
#pragma unroll
        for (int off = 1; off < 16; off <<= 1) {
            float o = __shfl_up(s, off, 64);
            if (t >= off) s += o;
        }
        wpre[t] = s;
    }
    __syncthreads();
    float pre = wv ? wpre[wv - 1] : 0.f;
    neg[(size_t)t * Hn + u] = v + pre;
}

// -------- K5: r_rep = neg @ lin_W^T + lin_b ----------------------------------
__global__ void k_rrep(const float* __restrict__ neg, const float* __restrict__ linW,
                       const float* __restrict__ linb, float* __restrict__ d_out) {
    int gid = blockIdx.x * 256 + threadIdx.x;
    if (gid < Bn * 6) {
        int b = gid / 6, o = gid - b * 6;
        float acc = linb[o];
        for (int u = 0; u < Hn; u++) acc += neg[(size_t)b * Hn + u] * linW[o * Hn + u];
        d_out[2 * Bn * 6 + gid] = acc;
    }
}

extern "C" void kernel_launch(void* const* d_in, const int* in_sizes, int n_in,
                              void* d_out, int out_size, void* d_ws, size_t ws_size,
                              hipStream_t stream) {
    const int*   word_id = (const int*)d_in[0];
    const int*   sen_len = (const int*)d_in[1];
    const int*   lwid    = (const int*)d_in[2];
    const float* emb     = (const float*)d_in[3];
    const float* W_ih    = (const float*)d_in[4];
    const float* W_hh    = (const float*)d_in[5];
    const float* b_ih    = (const float*)d_in[6];
    const float* b_hh    = (const float*)d_in[7];
    const float* linW    = (const float*)d_in[8];
    const float* linb    = (const float*)d_in[9];
    const float* llW     = (const float*)d_in[10];
    const float* llb     = (const float*)d_in[11];

    char* ws = (char*)d_ws;
    _Float16* table  = (_Float16*)(ws + OFF_TABLE);
    _Float16* oh16   = (_Float16*)(ws + OFF_OH16);
    uint4*    wfrag  = (uint4*)(ws + OFF_WFRAG);
    uint4*    wfragB = (uint4*)(ws + OFF_WFRAGB);
    float*    llwt   = (float*)(ws + OFF_LLWT);
    float*    lvp    = (float*)(ws + OFF_LV);
    float*    pn     = (float*)(ws + OFF_PN);
    float*    neg    = (float*)(ws + OFF_NEG);
    float*    outp   = (float*)d_out;

    k_prep<<<118, 256, 0, stream>>>(W_ih, W_hh, llW, wfrag, wfragB, llwt);
    k_table<<<(MPn / 64) * 2, 256, 0, stream>>>(emb, wfragB, b_ih, b_hh, table);
    k_label<<<Bn, 256, 0, stream>>>(lwid, emb, llwt, llb, lvp);
    k_lstm<<<Bn / 2, 256, 0, stream>>>(word_id, sen_len, table, wfrag, lvp, linW, linb, oh16, pn, outp);
    k_scan<<<Hn, 1024, 0, stream>>>(pn, neg);
    k_rrep<<<(Bn * 6 + 255) / 256, 256, 0, stream>>>(neg, linW, linb, outp);
}